// Round 1
// 626.274 us; speedup vs baseline: 1.0067x; 1.0067x over previous
//
#include <hip/hip_runtime.h>
#include <hip/hip_bf16.h>

// Problem constants (fixed by the reference file).
constexpr int N_NODES = 20000;
constexpr int N_EDGES = 640000;
constexpr int D = 128;          // D_IN == D_OUT == 128

typedef float  f32x4  __attribute__((ext_vector_type(4)));
typedef short  short8 __attribute__((ext_vector_type(8)));

// fp32 -> bf16 bits, round-to-nearest-even (scalar fallback)
__device__ inline short f2bf(float f) {
    unsigned u = __builtin_bit_cast(unsigned, f);
    u += 0x7fffu + ((u >> 16) & 1u);
    return (short)(u >> 16);
}
__device__ inline float bf2f(short s) {
    unsigned u = ((unsigned)(unsigned short)s) << 16;
    return __builtin_bit_cast(float, u);
}
// packed fp32x2 -> bf16x2 (RNE), single HW instruction.
// low 16 bits = bf16(a), high 16 bits = bf16(b)
__device__ inline unsigned cvt_pk_bf16(float a, float b) {
    unsigned r;
    asm("v_cvt_pk_bf16_f32 %0, %1, %2" : "=v"(r) : "v"(a), "v"(b));
    return r;
}

// ---------------------------------------------------------------------------
// Prep: convert W (128x128, row-major W[n][k]) into MFMA B-fragment-major
// bf16 arrays.  Fragment index: frag[(nt*4 + kt)*64 + lane], lane = quad*16 +
// row16, holding W[nt*16 + row16][kt*32 + quad*8 + j] for j=0..7.  A wave
// then loads its B fragment for (nt,kt) as one coalesced 16B/lane read.
// We -> fragE (plain bf16).  Wn -> fragH/fragL (hi/lo split for ~fp32 h).
// Also zeroes the counting-sort histogram (saves one memset dispatch on the
// serial critical path).
// ---------------------------------------------------------------------------
__global__ __launch_bounds__(256) void prep_kernel(
    const float* __restrict__ We, const float* __restrict__ Wn,
    short8* __restrict__ fragE, short8* __restrict__ fragH,
    short8* __restrict__ fragL, int* __restrict__ count)
{
    const int t = blockIdx.x * 256 + threadIdx.x;   // 2048 threads, 1 chunk each
    for (int i = t; i < N_NODES; i += 2048) count[i] = 0;

    const int n = t >> 4, k8 = t & 15;              // chunk = row n, 8-col group k8
    const int kt = k8 >> 2, q = k8 & 3;
    const int fi = ((n >> 4) * 4 + kt) * 64 + q * 16 + (n & 15);

    {
        const float4 x = *(const float4*)(We + n * D + k8 * 8);
        const float4 y = *(const float4*)(We + n * D + k8 * 8 + 4);
        short8 s;
        unsigned* sp = (unsigned*)&s;
        sp[0] = cvt_pk_bf16(x.x, x.y);
        sp[1] = cvt_pk_bf16(x.z, x.w);
        sp[2] = cvt_pk_bf16(y.x, y.y);
        sp[3] = cvt_pk_bf16(y.z, y.w);
        fragE[fi] = s;
    }
    {
        const float4 x = *(const float4*)(Wn + n * D + k8 * 8);
        const float4 y = *(const float4*)(Wn + n * D + k8 * 8 + 4);
        const float v[8] = {x.x, x.y, x.z, x.w, y.x, y.y, y.z, y.w};
        short8 hi, lo;
        #pragma unroll
        for (int j = 0; j < 8; ++j) {
            hi[j] = f2bf(v[j]);
            lo[j] = f2bf(v[j] - bf2f(hi[j]));
        }
        fragH[fi] = hi;
        fragL[fi] = lo;
    }
}

// ---------------------------------------------------------------------------
// Sort infrastructure: counting sort of edges by dst.
// ---------------------------------------------------------------------------
__global__ __launch_bounds__(256) void hist_kernel(
    const int* __restrict__ dst, int* __restrict__ count)
{
    const int e = blockIdx.x * 256 + threadIdx.x;
    if (e < N_EDGES) atomicAdd(&count[dst[e]], 1);
}

__global__ __launch_bounds__(1024) void scan_kernel(
    const int* __restrict__ count, int* __restrict__ cursor)
{
    constexpr int PER = 20;                    // 1024*20 = 20480 >= 20000
    __shared__ int tot[1024];
    const int tid = threadIdx.x;
    const int base = tid * PER;

    int local[PER];
    int s = 0;
    #pragma unroll
    for (int i = 0; i < PER; ++i) {
        const int idx = base + i;
        const int v = (idx < N_NODES) ? count[idx] : 0;
        local[i] = s;
        s += v;
    }
    tot[tid] = s;
    __syncthreads();
    for (int off = 1; off < 1024; off <<= 1) {
        const int add = (tid >= off) ? tot[tid - off] : 0;
        __syncthreads();
        tot[tid] += add;
        __syncthreads();
    }
    const int excl = tot[tid] - s;
    #pragma unroll
    for (int i = 0; i < PER; ++i) {
        const int idx = base + i;
        if (idx < N_NODES) cursor[idx] = excl + local[i];
    }
}

__global__ __launch_bounds__(256) void scatter_kernel(
    const int* __restrict__ dst, int* __restrict__ cursor,
    int* __restrict__ perm, int* __restrict__ dsts)
{
    const int e = blockIdx.x * 256 + threadIdx.x;
    if (e < N_EDGES) {
        const int d = dst[e];
        const int pos = atomicAdd(&cursor[d], 1);
        perm[pos] = e;
        dsts[pos] = d;
    }
}

// ---------------------------------------------------------------------------
// Kernel 1: h = nf @ Wn.T + bn via MFMA with bf16 hi/lo split (~fp32 exact):
//   nf = ah + al,  Wn = bh + bl;  acc = ah*bh + ah*bl + al*bh  (al*bl ~ 2^-18)
//   out = relu(h + res_w) / degs  (residual init);  h -> workspace.
// 64 rows/block (4 waves x 16 rows), B fragments from global fragH/fragL.
// ---------------------------------------------------------------------------
__global__ __launch_bounds__(256) void node_kernel(
    const float* __restrict__ nf, const float* __restrict__ degs,
    const short8* __restrict__ fragH, const short8* __restrict__ fragL,
    const float* __restrict__ bn, const float* __restrict__ res_w,
    float* __restrict__ h_ws, float* __restrict__ out)
{
    const int t = threadIdx.x;
    const int lane = t & 63, wave = t >> 6;
    const int quad = lane >> 4, row16 = lane & 15;
    const int mbase = blockIdx.x * 64 + wave * 16;

    // A fragments (hi/lo), row = mbase + row16
    const int arow = min(mbase + row16, N_NODES - 1);
    short8 ah[4], al[4];
    const float* p = nf + arow * D + quad * 8;
    #pragma unroll
    for (int kt = 0; kt < 4; ++kt) {
        const float4 x = *(const float4*)(p + kt * 32);
        const float4 y = *(const float4*)(p + kt * 32 + 4);
        const float v[8] = {x.x, x.y, x.z, x.w, y.x, y.y, y.z, y.w};
        #pragma unroll
        for (int j = 0; j < 8; ++j) {
            ah[kt][j] = f2bf(v[j]);
            al[kt][j] = f2bf(v[j] - bf2f(ah[kt][j]));
        }
    }

    // output rows this lane owns in the epilogue
    int   orow[4];
    float dinv[4];
    #pragma unroll
    for (int r = 0; r < 4; ++r) {
        orow[r] = mbase + quad * 4 + r;
        dinv[r] = 1.0f / degs[min(orow[r], N_NODES - 1)];
    }

    #pragma unroll
    for (int nt = 0; nt < 8; ++nt) {
        f32x4 acc = {0.f, 0.f, 0.f, 0.f};
        #pragma unroll
        for (int kt = 0; kt < 4; ++kt) {
            const short8 bh = fragH[(nt * 4 + kt) * 64 + lane];
            const short8 bl = fragL[(nt * 4 + kt) * 64 + lane];
            acc = __builtin_amdgcn_mfma_f32_16x16x32_bf16(al[kt], bh, acc, 0, 0, 0);
            acc = __builtin_amdgcn_mfma_f32_16x16x32_bf16(ah[kt], bl, acc, 0, 0, 0);
            acc = __builtin_amdgcn_mfma_f32_16x16x32_bf16(ah[kt], bh, acc, 0, 0, 0);
        }
        const int col = nt * 16 + row16;
        const float bnv = bn[col], rwv = res_w[col];
        #pragma unroll
        for (int r = 0; r < 4; ++r) {
            if (orow[r] < N_NODES) {
                const float h = acc[r] + bnv;
                h_ws[orow[r] * D + col] = h;
                out[orow[r] * D + col] = fmaxf(h + rwv, 0.0f) * dinv[r];
            }
        }
    }
}

// ---------------------------------------------------------------------------
// Kernel 2: edges in dst-sorted order (perm).
//   e   = ef[perm] @ We.T + be   (bf16 MFMA, B-fragments from global fragE)
//   msg = norm * relu(h[src] + e)
//   segmented sum over sorted-dst runs (per-wave LDS tile); one atomic/run.
//
// NOTE: tile[] and sdst[] are strictly WAVE-PRIVATE ([wave] slices, written
// and read only by the owning wave).  Within-wave LDS ordering is guaranteed
// by the in-order DS pipe + compiler lgkmcnt insertion, so there are NO
// __syncthreads() here — waves slip freely so one wave's serial segmented
// scan + atomics overlap another wave's MFMA/gather phase.
// ---------------------------------------------------------------------------
constexpr int TILE_LD = 33;               // 32 m + 1 pad: conflict-free both ways

__global__ __launch_bounds__(256) void edge_kernel(
    const float* __restrict__ ef, const float* __restrict__ norm,
    const int* __restrict__ src,
    const int* __restrict__ perm, const int* __restrict__ dsts,
    const short8* __restrict__ fragE, const float* __restrict__ be,
    const float* __restrict__ h, float* __restrict__ out)
{
    __shared__ float tile[4][32 * TILE_LD]; // 16896 B: per-wave [col][m]
    __shared__ int   sdst[4][32];           // 512 B

    const int t = threadIdx.x;
    const int lane  = t & 63;
    const int quad  = lane >> 4;
    const int row16 = lane & 15;
    const int wave  = t >> 6;
    const int p0 = blockIdx.x * 128 + wave * 32;   // 32 sorted positions/wave

    if (lane < 32) sdst[wave][lane] = dsts[p0 + lane];

    // ---- A fragments: gather edge rows via perm, fp32 -> bf16 (HW cvt_pk),
    // keep in regs
    short8 afr[2][4];
    #pragma unroll
    for (int mt = 0; mt < 2; ++mt) {
        const int erow = perm[p0 + mt * 16 + row16];
        const float* p = ef + erow * D + quad * 8;
        #pragma unroll
        for (int kt = 0; kt < 4; ++kt) {
            const float4 x = *(const float4*)(p + kt * 32);
            const float4 y = *(const float4*)(p + kt * 32 + 4);
            short8 a;
            unsigned* ap = (unsigned*)&a;
            ap[0] = cvt_pk_bf16(x.x, x.y);
            ap[1] = cvt_pk_bf16(x.z, x.w);
            ap[2] = cvt_pk_bf16(y.x, y.y);
            ap[3] = cvt_pk_bf16(y.z, y.w);
            afr[mt][kt] = a;
        }
    }

    // ---- Edge metadata (src, norm) for epilogue rows this lane owns
    int   sidx[2][4];
    float nrm[2][4];
    #pragma unroll
    for (int mt = 0; mt < 2; ++mt) {
        #pragma unroll
        for (int r = 0; r < 4; ++r) {
            const int pe = perm[p0 + mt * 16 + quad * 4 + r];
            sidx[mt][r] = src[pe];
            nrm[mt][r]  = norm[pe];
        }
    }

    // ---- 4 groups of 2 n-tiles: MFMA + epilogue to LDS, then segmented scan
    for (int g = 0; g < 4; ++g) {
        #pragma unroll
        for (int t2 = 0; t2 < 2; ++t2) {
            const int nt = g * 2 + t2;
            short8 bfr[4];
            #pragma unroll
            for (int kt = 0; kt < 4; ++kt)
                bfr[kt] = fragE[(nt * 4 + kt) * 64 + lane];

            f32x4 acc0 = {0.f, 0.f, 0.f, 0.f};
            f32x4 acc1 = {0.f, 0.f, 0.f, 0.f};
            #pragma unroll
            for (int kt = 0; kt < 4; ++kt) {
                acc0 = __builtin_amdgcn_mfma_f32_16x16x32_bf16(afr[0][kt], bfr[kt], acc0, 0, 0, 0);
                acc1 = __builtin_amdgcn_mfma_f32_16x16x32_bf16(afr[1][kt], bfr[kt], acc1, 0, 0, 0);
            }

            // epilogue: C/D layout col = lane&15, row m = quad*4 + r
            const int col = nt * 16 + row16;
            const float bev = be[col];
            float* tp = &tile[wave][(t2 * 16 + row16) * TILE_LD];
            #pragma unroll
            for (int r = 0; r < 4; ++r) {
                const int m0 = quad * 4 + r;
                const float hv0 = h[sidx[0][r] * D + col];
                tp[m0] = nrm[0][r] * fmaxf(hv0 + acc0[r] + bev, 0.0f);
                const int m1 = m0 + 16;
                const float hv1 = h[sidx[1][r] * D + col];
                tp[m1] = nrm[1][r] * fmaxf(hv1 + acc1[r] + bev, 0.0f);
            }
        }

        // segmented scan: lane = col*2 + chunk; chunk covers 16 sorted rows.
        // (wave-private: in-order DS pipe orders the tile writes above vs the
        // reads below; no barrier needed)
        {
            const int c = lane >> 1;
            const int chunk = lane & 1;
            const int mbeg = chunk * 16;
            const float* sp = &tile[wave][c * TILE_LD];
            const int gcol = g * 32 + c;
            int cur = sdst[wave][mbeg];
            float sum = 0.0f;
            #pragma unroll
            for (int m = mbeg; m < mbeg + 16; ++m) {
                const int dm = sdst[wave][m];
                const float v = sp[m];
                if (dm != cur) {
                    atomicAdd(&out[cur * D + gcol], sum);
                    sum = 0.0f;
                    cur = dm;
                }
                sum += v;
            }
            atomicAdd(&out[cur * D + gcol], sum);
        }
    }
}

extern "C" void kernel_launch(void* const* d_in, const int* in_sizes, int n_in,
                              void* d_out, int out_size, void* d_ws, size_t ws_size,
                              hipStream_t stream) {
    const float* node_feats = (const float*)d_in[0];
    const float* edge_feats = (const float*)d_in[1];
    const float* degs       = (const float*)d_in[2];
    const float* norm       = (const float*)d_in[3];
    const int*   src        = (const int*)d_in[4];
    const int*   dst        = (const int*)d_in[5];
    const float* Wn         = (const float*)d_in[6];
    const float* bn         = (const float*)d_in[7];
    const float* We         = (const float*)d_in[8];
    const float* be         = (const float*)d_in[9];
    const float* res_w      = (const float*)d_in[10];

    float* out = (float*)d_out;

    // Workspace layout (bytes):
    //   h:      [0,        10240000)   N*D fp32
    //   perm:   [10240000, 12800000)   E i32
    //   dsts:   [12800000, 15360000)   E i32
    //   count:  [15360000, 15440000)   N i32 (doubles as scatter cursor)
    //   fragE:  [15500000, +32768)     We bf16 fragments
    //   fragH:  [15600000, +32768)     Wn hi fragments
    //   fragL:  [15700000, +32768)     Wn lo fragments
    char* ws = (char*)d_ws;
    float*  h_ws  = (float*)(ws);
    int*    perm  = (int*)(ws + 10240000);
    int*    dsts  = (int*)(ws + 12800000);
    int*    count = (int*)(ws + 15360000);
    short8* fragE = (short8*)(ws + 15500000);
    short8* fragH = (short8*)(ws + 15600000);
    short8* fragL = (short8*)(ws + 15700000);

    // 0) weight fragments + histogram zero
    prep_kernel<<<8, 256, 0, stream>>>(We, Wn, fragE, fragH, fragL, count);

    // 1) counting sort of edges by dst
    hist_kernel<<<(N_EDGES + 255) / 256, 256, 0, stream>>>(dst, count);
    scan_kernel<<<1, 1024, 0, stream>>>(count, count);
    scatter_kernel<<<(N_EDGES + 255) / 256, 256, 0, stream>>>(dst, count, perm, dsts);

    // 2) node path: writes h and the residual term into out
    node_kernel<<<(N_NODES + 63) / 64, 256, 0, stream>>>(node_feats, degs, fragH, fragL,
                                                         bn, res_w, h_ws, out);

    // 3) edge path: sorted-order GEMM + segmented-sum aggregation
    edge_kernel<<<N_EDGES / 128, 256, 0, stream>>>(edge_feats, norm, src, perm, dsts,
                                                   fragE, be, h_ws, out);
}